// Round 9
// baseline (442.768 us; speedup 1.0000x reference)
//
#include <hip/hip_runtime.h>
#include <hip/hip_bf16.h>

typedef __bf16 bf16_t;
typedef __attribute__((ext_vector_type(8))) __bf16 bf16x8;
typedef __attribute__((ext_vector_type(4))) __bf16 bf16x4;
typedef __attribute__((ext_vector_type(4))) float floatx4;
typedef __attribute__((ext_vector_type(4))) int intx4;
typedef __attribute__((ext_vector_type(4))) unsigned uintx4;

#define NN 8192
#define FIN 256
#define FOUT 64
#define GAT_ALPHA 0.2f
#define JSPLIT 4
#define JSEG (NN / JSPLIT)          // 2048 j per block
#define NSTEPS (JSEG / 32)          // 64 K-steps
#define NWORDS (NN / 32)            // 256 mask words per row

// ---------------------------------------------------------------------------
// Kernel P: pack adj (int32 0/1, 256 MB) -> bitmask (8 MB), j-ordered.
// Thread t packs ints [32t, 32t+32) -> word t (bit k = adj[32t+k] > 0).
// Wave reads 8 KB contiguous (L1 absorbs per-instr stride) -> streams at
// near copy-BW. This is the ONLY kernel that touches adj.
// ---------------------------------------------------------------------------
__global__ __launch_bounds__(256) void adj_pack_kernel(
    const int* __restrict__ adj, unsigned* __restrict__ mask)
{
    const size_t t = (size_t)blockIdx.x * 256 + threadIdx.x;
    const int* p = adj + t * 32;
    unsigned m = 0;
    #pragma unroll
    for (int g = 0; g < 8; g++) {
        intx4 v = *(const intx4*)(p + g * 4);
        #pragma unroll
        for (int e = 0; e < 4; e++)
            m |= (v[e] > 0) ? (1u << (g * 4 + e)) : 0u;
    }
    mask[t] = m;
}

// ---------------------------------------------------------------------------
// Kernel A: h = input @ W (fp32 in -> bf16 MFMA). Outputs:
//   hT [64][8192] bf16, E1/F1 fp32 [8192], ef2 packed (bf16 E2 | bf16 F2<<16).
// ---------------------------------------------------------------------------
__global__ __launch_bounds__(256) void gat_h_kernel(
    const float* __restrict__ input,    // [8192][256] fp32
    const float* __restrict__ W,        // [256][64] fp32
    const float* __restrict__ a,        // [128] fp32
    bf16_t* __restrict__ hT,            // [64][8192] bf16
    float* __restrict__ e1g, float* __restrict__ f1g,
    unsigned* __restrict__ ef2g)        // [8192] packed bf16 pair
{
    alignas(16) __shared__ bf16_t in_lds[32][264];
    alignas(16) __shared__ bf16_t wt_lds[64][264];
    __shared__ float h_lds[32][65];

    const int t  = threadIdx.x;
    const int i0 = blockIdx.x * 32;

    #pragma unroll
    for (int v = 0; v < 8; v++) {
        int u  = v * 256 + t;
        int i  = u >> 6;
        int k4 = (u & 63) * 4;
        floatx4 x = *(const floatx4*)(input + (size_t)(i0 + i) * FIN + k4);
        bf16x4 b;
        #pragma unroll
        for (int e = 0; e < 4; e++) b[e] = (bf16_t)x[e];
        *(bf16x4*)(&in_lds[i][k4]) = b;
    }
    #pragma unroll
    for (int v = 0; v < 16; v++) {
        int u  = v * 256 + t;
        int k  = u >> 4;
        int f4 = (u & 15) * 4;
        floatx4 wv = *(const floatx4*)(W + k * FOUT + f4);
        #pragma unroll
        for (int e = 0; e < 4; e++) wt_lds[f4 + e][k] = (bf16_t)wv[e];
    }
    __syncthreads();

    const int wave = t >> 6;
    const int lane = t & 63;
    const int i16  = (wave & 1) * 16;
    const int f32  = (wave >> 1) * 32;
    const int lm   = lane & 15;
    const int lq   = lane >> 4;

    floatx4 acc0 = {0.f, 0.f, 0.f, 0.f};
    floatx4 acc1 = {0.f, 0.f, 0.f, 0.f};
    #pragma unroll
    for (int ks = 0; ks < 8; ks++) {
        int ko = ks * 32 + lq * 8;
        bf16x8 af = *(const bf16x8*)(&in_lds[i16 + lm][ko]);
        bf16x8 b0 = *(const bf16x8*)(&wt_lds[f32 + lm][ko]);
        bf16x8 b1 = *(const bf16x8*)(&wt_lds[f32 + 16 + lm][ko]);
        acc0 = __builtin_amdgcn_mfma_f32_16x16x32_bf16(af, b0, acc0, 0, 0, 0);
        acc1 = __builtin_amdgcn_mfma_f32_16x16x32_bf16(af, b1, acc1, 0, 0, 0);
    }

    #pragma unroll
    for (int c = 0; c < 2; c++) {
        floatx4 acc = c ? acc1 : acc0;
        int f  = f32 + c * 16 + lm;
        int ib = i0 + i16 + lq * 4;
        bf16x4 hp;
        #pragma unroll
        for (int r = 0; r < 4; r++) hp[r] = (bf16_t)acc[r];
        *(bf16x4*)(hT + (size_t)f * NN + ib) = hp;
    }
    #pragma unroll
    for (int c = 0; c < 2; c++) {
        floatx4 acc = c ? acc1 : acc0;
        #pragma unroll
        for (int r = 0; r < 4; r++)
            h_lds[i16 + lq * 4 + r][f32 + c * 16 + lm] = acc[r];
    }
    __syncthreads();

    if (t < 64) {
        int r   = t & 31;
        int sel = t >> 5;
        const float* av = a + sel * FOUT;
        float s = 0.f;
        #pragma unroll 8
        for (int f = 0; f < FOUT; f++) s += h_lds[r][f] * av[f];
        int gi = i0 + r;
        float E = expf(s);
        float F = expf(GAT_ALPHA * s);
        if (sel == 0) {
            e1g[gi] = E; f1g[gi] = F;
        } else {
            unsigned eb = __builtin_bit_cast(unsigned short, (bf16_t)E);
            unsigned fb = __builtin_bit_cast(unsigned short, (bf16_t)F);
            ef2g[gi] = (fb << 16) | eb;
        }
    }
}

// ---------------------------------------------------------------------------
// Kernel B: bitmask-driven fused softmax+aggregation. No LDS, no barriers.
// 128 thr = 2 waves; wave owns 16 rows x JSEG. Per K-step (32 j): mask byte
// per lane (from a uintx4 covering 4 steps, same addr across q -> L1),
// ef2 2x uintx4 + hT 4x bf16x8 (all L2-resident), w built in A-frag layout,
// 5 MFMA (4 acc + ones-B rowsum). All global streams are tiny & cache-hot;
// HBM sees almost nothing. VALU-bound by design.
// w = bit ? max(E1*E2, F1*F2) : 0   [= exp(leaky_relu(s1+s2)) masked]
// ---------------------------------------------------------------------------
__global__ __launch_bounds__(128, 2) void gat_att_kernel(
    const unsigned* __restrict__ mask,  // [8192][256] packed adj bits
    const bf16_t* __restrict__ hT,      // [64][8192] bf16
    const float* __restrict__ e1g, const float* __restrict__ f1g,
    const unsigned* __restrict__ ef2g,  // [8192] packed
    float* __restrict__ pacc,           // [JSPLIT][8192][64]
    float* __restrict__ prs)            // [JSPLIT][8192]
{
    const int t    = threadIdx.x;
    const int wave = t >> 6;
    const int lane = t & 63;
    const int m    = lane & 15;         // A-frag row / C col f
    const int q    = lane >> 4;         // quad: k = q*8+e
    const int i0   = blockIdx.x * 32 + wave * 16;
    const int js   = blockIdx.y;
    const int jb   = js * JSEG;
    const int row  = i0 + m;

    const float E1 = e1g[row];
    const float F1 = f1g[row];

    const unsigned* mp  = mask + (size_t)row * NWORDS + jb / 32;
    const unsigned* efp = ef2g + jb + q * 8;
    const bf16_t*   htp = hT + (size_t)m * NN + jb + q * 8;

    floatx4 acc[4];
    #pragma unroll
    for (int c = 0; c < 4; c++) acc[c] = (floatx4){0.f, 0.f, 0.f, 0.f};
    floatx4 acc4 = {0.f, 0.f, 0.f, 0.f};   // rowsum via ones-B MFMA

    bf16x8 ones8;
    #pragma unroll
    for (int e = 0; e < 8; e++) ones8[e] = (bf16_t)1.0f;

    // prefetch registers (mask 4 steps ahead; ef/hT 1 step ahead)
    uintx4 mw = *(const uintx4*)(mp);
    uintx4 e0 = *(const uintx4*)(efp);
    uintx4 e1 = *(const uintx4*)(efp + 4);
    bf16x8 hb[4];
    #pragma unroll
    for (int c = 0; c < 4; c++)
        hb[c] = *(const bf16x8*)(htp + (size_t)c * 16 * NN);

    for (int g = 0; g < NSTEPS / 4; g++) {
        uintx4 mc = mw;
        if (g + 1 < NSTEPS / 4) mw = *(const uintx4*)(mp + (g + 1) * 4);

        #pragma unroll
        for (int ks = 0; ks < 4; ks++) {
            const int s = g * 4 + ks;
            const unsigned bits = (mc[ks] >> (q * 8)) & 0xFFu;

            uintx4 ce0 = e0, ce1 = e1;
            bf16x8 ch0 = hb[0], ch1 = hb[1], ch2 = hb[2], ch3 = hb[3];
            if (s + 1 < NSTEPS) {
                e0 = *(const uintx4*)(efp + (s + 1) * 32);
                e1 = *(const uintx4*)(efp + (s + 1) * 32 + 4);
                #pragma unroll
                for (int c = 0; c < 4; c++)
                    hb[c] = *(const bf16x8*)(htp + (size_t)c * 16 * NN
                                             + (s + 1) * 32);
            }

            bf16x8 wf;
            #pragma unroll
            for (int e = 0; e < 8; e++) {
                unsigned v = (e < 4) ? ce0[e] : ce1[e - 4];
                float e2 = __builtin_bit_cast(float, v << 16);
                float f2 = __builtin_bit_cast(float, v & 0xffff0000u);
                float pv = fmaxf(E1 * e2, F1 * f2);
                wf[e] = (bf16_t)((bits & (1u << e)) ? pv : 0.f);
            }
            acc[0] = __builtin_amdgcn_mfma_f32_16x16x32_bf16(wf, ch0, acc[0], 0, 0, 0);
            acc[1] = __builtin_amdgcn_mfma_f32_16x16x32_bf16(wf, ch1, acc[1], 0, 0, 0);
            acc[2] = __builtin_amdgcn_mfma_f32_16x16x32_bf16(wf, ch2, acc[2], 0, 0, 0);
            acc[3] = __builtin_amdgcn_mfma_f32_16x16x32_bf16(wf, ch3, acc[3], 0, 0, 0);
            acc4   = __builtin_amdgcn_mfma_f32_16x16x32_bf16(wf, ones8, acc4, 0, 0, 0);
        }
    }

    // rowsum: acc4[r] = rowsum(row q*4+r) replicated across cols; m==0 writes
    if (m == 0) {
        #pragma unroll
        for (int r = 0; r < 4; r++)
            prs[(size_t)js * NN + i0 + q * 4 + r] = acc4[r];
    }

    // partial acc: C layout col=m (f), row=q*4+r
    float* pa = pacc + (size_t)js * NN * FOUT;
    #pragma unroll
    for (int c = 0; c < 4; c++) {
        #pragma unroll
        for (int r = 0; r < 4; r++)
            pa[(size_t)(i0 + q * 4 + r) * FOUT + c * 16 + m] = acc[c][r];
    }
}

// ---------------------------------------------------------------------------
// Kernel C: combine JSPLIT partials, normalize, ELU, store fp32.
// ---------------------------------------------------------------------------
__global__ __launch_bounds__(256) void gat_combine_kernel(
    const float* __restrict__ pacc,     // [JSPLIT][8192][64]
    const float* __restrict__ prs,      // [JSPLIT][8192]
    float* __restrict__ out)            // [8192][64]
{
    int idx = blockIdx.x * 256 + threadIdx.x;
    int i   = idx >> 4;
    floatx4 s = {0.f, 0.f, 0.f, 0.f};
    float rs  = 0.f;
    #pragma unroll
    for (int js = 0; js < JSPLIT; js++) {
        s  += *(const floatx4*)(pacc + (size_t)js * NN * FOUT + (size_t)idx * 4);
        rs += prs[(size_t)js * NN + i];
    }
    float rinv = (rs > 0.f) ? 1.0f / rs : 0.f;
    floatx4 r;
    #pragma unroll
    for (int e = 0; e < 4; e++) {
        float x = s[e] * rinv;
        r[e] = (x > 0.f) ? x : (expf(x) - 1.0f);
    }
    *(floatx4*)(out + (size_t)idx * 4) = r;
}

// ---------------------------------------------------------------------------
extern "C" void kernel_launch(void* const* d_in, const int* in_sizes, int n_in,
                              void* d_out, int out_size, void* d_ws, size_t ws_size,
                              hipStream_t stream) {
    const float* input = (const float*)d_in[0];     // [8192][256] fp32
    const int*   adj   = (const int*)d_in[1];       // [8192][8192] int32
    const float* W     = (const float*)d_in[2];     // [256][64] fp32
    const float* a     = (const float*)d_in[3];     // [128] fp32
    float*       out   = (float*)d_out;             // [8192][64] fp32

    char* ws = (char*)d_ws;
    bf16_t*   hT   = (bf16_t*)ws;                   // 1 MiB
    float*    e1g  = (float*)(ws + (1 << 20));
    float*    f1g  = e1g + NN;
    unsigned* ef2g = (unsigned*)(f1g + NN);
    unsigned* mask = ef2g + NN;                     // 8 MiB
    float*    pacc = (float*)(mask + (size_t)NN * NWORDS);   // 8 MiB
    float*    prs  = pacc + (size_t)JSPLIT * NN * FOUT;

    adj_pack_kernel<<<(NN / 32) * (NN / 256), 256, 0, stream>>>(adj, mask);

    gat_h_kernel<<<NN / 32, 256, 0, stream>>>(input, W, a, hT, e1g, f1g, ef2g);

    dim3 gridB(NN / 32, JSPLIT);
    gat_att_kernel<<<gridB, 128, 0, stream>>>(mask, hT, e1g, f1g, ef2g,
                                              pacc, prs);

    gat_combine_kernel<<<NN * FOUT / 4 / 256, 256, 0, stream>>>(pacc, prs, out);
}